// Round 1
// baseline (195.686 us; speedup 1.0000x reference)
//
#include <hip/hip_runtime.h>

// Hierarchical softmax: B=4096, NHID=512, BR=32, DEPTH=3, V=32768.
// bucket g = lab>>5. node0=0 (step g>>5), node1=1+(g>>5) (step g&31),
// node2=33+g (step lab&31). out[b] = prod_k softmax(x_b @ W[node_k])[step_k]
//
// R10: single-kernel restructure. One block per bucket g (1024 blocks,
// 192 threads, wave k = level k, R9's verified double-buffered W prefetch
// core). Replaces the R9 serial single-block counting sort + dependent
// second launch with per-block self-discovery: each block scans the 4096
// labels as int4 (16 KB, L2-broadcast) and compacts matches via shared
// atomics -- sample order is irrelevant since outputs are per-sample.
// W addresses depend only on g, so each wave primes its first 8-load W
// batch BEFORE the scan: the coldest HBM latency hides under scan+stage.
// Buckets with >8 samples (Poisson(4): ~2%) loop over chunks of 8.

#define NHID  512
#define BR    32
#define BATCH 4096
#define NBUCK 1024
#define SMAX  8
#define CAP   128   // max samples per bucket; Poisson(4) max ~16, 128 is safe

#define FMA4(A, xv, wv_) do { \
    (A).x = fmaf((xv), (wv_).x, (A).x); \
    (A).y = fmaf((xv), (wv_).y, (A).y); \
    (A).z = fmaf((xv), (wv_).z, (A).z); \
    (A).w = fmaf((xv), (wv_).w, (A).w); } while (0)

__global__ __launch_bounds__(192) void hsm_bucket(
    const float* __restrict__ inputs,
    const int* __restrict__ labels,
    const float* __restrict__ W,
    float* __restrict__ out)
{
    __shared__ float xsT[NHID * SMAX];   // 16 KB, xsT[h][s0..7]
    __shared__ float pk[3][SMAX];
    __shared__ int   sids[CAP];
    __shared__ int   slab[CAP];
    __shared__ int   scnt;

    const int g    = blockIdx.x;
    const int tid  = threadIdx.x;
    const int k    = tid >> 6;    // wave = tree level
    const int lane = tid & 63;
    const int colg = lane & 7;    // float4 column group
    const int hsel = lane >> 3;   // h strip: h = 8i + hsel

    const int node   = (k == 0) ? 0 : (k == 1) ? 1 + (g >> 5) : 33 + g;
    const int step01 = (k == 0) ? (g >> 5) : (g & 31);

    const float4* wp = (const float4*)(W + (size_t)node * (NHID * BR))
                       + hsel * 8 + colg;
    const float4* xp = (const float4*)xsT + hsel * 2;  // float4 idx = 2h

    // ---- prime first W batch NOW (addresses depend only on g, not labels);
    // its HBM latency hides under the label scan + x staging below.
    float4 wcur[8], wnxt[8];
    #pragma unroll
    for (int j = 0; j < 8; ++j) wcur[j] = wp[j * 64];

    if (tid == 0) scnt = 0;
    __syncthreads();

    // ---- self-discovery: scan all labels as int4, compact matches ----
    const int4* l4 = (const int4*)labels;
    for (int i = tid; i < BATCH / 4; i += 192) {
        const int4 v = l4[i];
        if ((v.x >> 5) == g) { int p = atomicAdd(&scnt, 1); if (p < CAP) { sids[p] = 4*i;   slab[p] = v.x; } }
        if ((v.y >> 5) == g) { int p = atomicAdd(&scnt, 1); if (p < CAP) { sids[p] = 4*i+1; slab[p] = v.y; } }
        if ((v.z >> 5) == g) { int p = atomicAdd(&scnt, 1); if (p < CAP) { sids[p] = 4*i+2; slab[p] = v.z; } }
        if ((v.w >> 5) == g) { int p = atomicAdd(&scnt, 1); if (p < CAP) { sids[p] = 4*i+3; slab[p] = v.w; } }
    }
    __syncthreads();
    const int mt = min(scnt, CAP);
    if (mt == 0) return;   // ~1.8% of buckets are empty

    for (int c0 = 0; c0 < mt; c0 += SMAX) {
        if (c0 > 0) {   // re-prime W stream for a rare 2nd chunk
            #pragma unroll
            for (int j = 0; j < 8; ++j) wcur[j] = wp[j * 64];
        }

        // ---- stage xsT[h][0..7] (32 B rows), zero-pad unused slots ----
        for (int h = tid; h < NHID; h += 192) {
            float v[SMAX];
            #pragma unroll
            for (int s = 0; s < SMAX; ++s) {
                const int q = c0 + s;
                v[s] = (q < mt) ? inputs[(size_t)sids[q] * NHID + h] : 0.0f;
            }
            float4* dst = (float4*)&xsT[h * SMAX];
            dst[0] = make_float4(v[0], v[1], v[2], v[3]);
            dst[1] = make_float4(v[4], v[5], v[6], v[7]);
        }
        __syncthreads();

        float4 acc[SMAX];
        #pragma unroll
        for (int s = 0; s < SMAX; ++s) acc[s] = make_float4(0, 0, 0, 0);

        // ---- W stream with explicit double-buffered register prefetch ----
        #pragma unroll
        for (int ii = 0; ii < 64; ii += 8) {
            if (ii + 8 < 64) {
                #pragma unroll
                for (int j = 0; j < 8; ++j) wnxt[j] = wp[(ii + 8 + j) * 64];
            }
            #pragma unroll
            for (int j = 0; j < 8; ++j) {
                const float4 xa = xp[(ii + j) * 16];
                const float4 xb = xp[(ii + j) * 16 + 1];
                FMA4(acc[0], xa.x, wcur[j]); FMA4(acc[1], xa.y, wcur[j]);
                FMA4(acc[2], xa.z, wcur[j]); FMA4(acc[3], xa.w, wcur[j]);
                FMA4(acc[4], xb.x, wcur[j]); FMA4(acc[5], xb.y, wcur[j]);
                FMA4(acc[6], xb.z, wcur[j]); FMA4(acc[7], xb.w, wcur[j]);
            }
            #pragma unroll
            for (int j = 0; j < 8; ++j) wcur[j] = wnxt[j];
        }

        // butterfly-reduce over hsel (masks 8,16,32): all lanes full sums
        #pragma unroll
        for (int s = 0; s < SMAX; ++s) {
            #pragma unroll
            for (int mm = 8; mm <= 32; mm <<= 1) {
                acc[s].x += __shfl_xor(acc[s].x, mm);
                acc[s].y += __shfl_xor(acc[s].y, mm);
                acc[s].z += __shfl_xor(acc[s].z, mm);
                acc[s].w += __shfl_xor(acc[s].w, mm);
            }
        }

        // per-sample softmax over 32 logits (8 colg lanes x 4 comps)
        #pragma unroll
        for (int s = 0; s < SMAX; ++s) {
            float4 a = acc[s];
            float mx = fmaxf(fmaxf(a.x, a.y), fmaxf(a.z, a.w));
            #pragma unroll
            for (int mm = 1; mm <= 4; mm <<= 1) mx = fmaxf(mx, __shfl_xor(mx, mm));
            float es = expf(a.x - mx) + expf(a.y - mx) + expf(a.z - mx) + expf(a.w - mx);
            #pragma unroll
            for (int mm = 1; mm <= 4; mm <<= 1) es += __shfl_xor(es, mm);

            const int step = (k == 2) ? (slab[c0 + s] & 31) : step01;
            const int e = step & 3;
            const float vv = (e == 0) ? a.x : (e == 1) ? a.y : (e == 2) ? a.z : a.w;
            const float sl = __shfl(vv, step >> 2);
            const float p = expf(sl - mx) / es;
            if (lane == 0) pk[k][s] = p;
        }
        __syncthreads();

        if (tid < SMAX && c0 + tid < mt)
            out[sids[c0 + tid]] = pk[0][tid] * pk[1][tid] * pk[2][tid];
    }
}

extern "C" void kernel_launch(void* const* d_in, const int* in_sizes, int n_in,
                              void* d_out, int out_size, void* d_ws, size_t ws_size,
                              hipStream_t stream)
{
    const float* inputs = (const float*)d_in[0];
    const int*   labels = (const int*)d_in[1];
    const float* W      = (const float*)d_in[2];
    float* out = (float*)d_out;

    hsm_bucket<<<dim3(NBUCK), dim3(192), 0, stream>>>(inputs, labels, W, out);
}

// Round 2
// 150.941 us; speedup vs baseline: 1.2964x; 1.2964x over previous
//
#include <hip/hip_runtime.h>

// Hierarchical softmax: B=4096, NHID=512, BR=32, DEPTH=3, V=32768.
// bucket g = lab>>5. node0=0 (step g>>5), node1=1+(g>>5) (step g&31),
// node2=33+g (step lab&31). out[b] = prod_k softmax(x_b @ W[node_k])[step_k]
//
// R11: R10 measured 388 GB/s (4.8% peak) at 45 MB traffic -> pure MLP
// failure: ~570 B in flight per CU despite the wcur/wnxt register double
// buffer (compiler serialized it), and VGPR=160 capped residency at 2
// blocks/CU. Fix: stream W via global_load_lds (width 16) into per-wave
// double-buffered 4 KB LDS chunks with explicit counted s_waitcnt vmcnt(4)
// (T4: never drain to 0 in steady state). 4-8 KB guaranteed in flight per
// wave by construction, zero VGPR cost (drops wcur/wnxt = -64 VGPRs),
// 3 blocks/CU by LDS (41.6 KB). Chunks 0,1 issued BEFORE the label scan
// (W address depends only on g) so the cold prime hides under scan+stage.
// Compute core (scan, xsT, FMA mapping, butterfly reduce, softmax) is the
// verified R10 code; W fragments now come from LDS as contiguous
// ds_read_b128 (float4 idx == lane: conflict-free).

#define NHID   512
#define BR     32
#define BATCH  4096
#define NBUCK  1024
#define SMAX   8
#define CAP    64              // max samples/bucket tracked; Poisson(4) max ~16
#define CROWS  32              // W rows per chunk
#define CFLT   (CROWS * BR)    // floats per chunk = 1024 (4 KB)
#define NCHUNK (NHID / CROWS)  // 16

#define FMA4(A, xv, wv_) do { \
    (A).x = fmaf((xv), (wv_).x, (A).x); \
    (A).y = fmaf((xv), (wv_).y, (A).y); \
    (A).z = fmaf((xv), (wv_).z, (A).z); \
    (A).w = fmaf((xv), (wv_).w, (A).w); } while (0)

// async global->LDS, 16 B per lane. LDS dest is wave-uniform base
// (HW adds lane*16); global src is per-lane.
__device__ __forceinline__ void gload_lds16(const float* g, float* l) {
    __builtin_amdgcn_global_load_lds(
        (const __attribute__((address_space(1))) void*)g,
        (__attribute__((address_space(3))) void*)l, 16, 0, 0);
}

__global__ __launch_bounds__(192) void hsm_bucket(
    const float* __restrict__ inputs,
    const int* __restrict__ labels,
    const float* __restrict__ W,
    float* __restrict__ out)
{
    __shared__ float xsT[NHID * SMAX];    // 16 KB, xsT[h][s0..7]
    __shared__ float wb[3][2][CFLT];      // 24 KB: per-wave double-buffered W
    __shared__ float pk[3][SMAX];
    __shared__ int   sids[CAP];
    __shared__ int   slab[CAP];
    __shared__ int   scnt;

    const int g    = blockIdx.x;
    const int tid  = threadIdx.x;
    const int k    = tid >> 6;    // wave = tree level
    const int lane = tid & 63;
    const int colg = lane & 7;    // float4 column group
    const int hsel = lane >> 3;   // h strip: h = 8i + hsel

    const int node   = (k == 0) ? 0 : (k == 1) ? 1 + (g >> 5) : 33 + g;
    const int step01 = (k == 0) ? (g >> 5) : (g & 31);

    const float* wglob  = W + (size_t)node * (NHID * BR) + lane * 4;
    float* const wbase0 = wb[k][0];
    float* const wbase1 = wb[k][1];

    // issue one 4 KB chunk (4 x global_load_lds_dwordx4, 1 KB each)
    #define ISSUE(c, bptr) do { \
        const float* gs_ = wglob + (size_t)(c) * CFLT; \
        gload_lds16(gs_,       (bptr)); \
        gload_lds16(gs_ + 256, (bptr) + 256); \
        gload_lds16(gs_ + 512, (bptr) + 512); \
        gload_lds16(gs_ + 768, (bptr) + 768); } while (0)

    // ---- prime chunks 0,1 NOW: cold-HBM latency hides under scan+stage ----
    ISSUE(0, wbase0);
    ISSUE(1, wbase1);

    if (tid == 0) scnt = 0;
    __syncthreads();

    // ---- self-discovery: scan all labels as int4, compact matches ----
    const int4* l4 = (const int4*)labels;
    for (int i = tid; i < BATCH / 4; i += 192) {
        const int4 v = l4[i];
        if ((v.x >> 5) == g) { int p = atomicAdd(&scnt, 1); if (p < CAP) { sids[p] = 4*i;   slab[p] = v.x; } }
        if ((v.y >> 5) == g) { int p = atomicAdd(&scnt, 1); if (p < CAP) { sids[p] = 4*i+1; slab[p] = v.y; } }
        if ((v.z >> 5) == g) { int p = atomicAdd(&scnt, 1); if (p < CAP) { sids[p] = 4*i+2; slab[p] = v.z; } }
        if ((v.w >> 5) == g) { int p = atomicAdd(&scnt, 1); if (p < CAP) { sids[p] = 4*i+3; slab[p] = v.w; } }
    }
    __syncthreads();
    const int mt = min(scnt, CAP);
    if (mt == 0) {   // ~1.8% of buckets: drain DMA before block retires
        asm volatile("s_waitcnt vmcnt(0)" ::: "memory");
        return;
    }

    const float4* xf = (const float4*)xsT;

    for (int c0 = 0; c0 < mt; c0 += SMAX) {
        if (c0 > 0) {   // rare 2nd chunk of samples: re-prime W stream
            ISSUE(0, wbase0);
            ISSUE(1, wbase1);
        }

        // ---- stage xsT[h][0..7] (32 B rows), zero-pad unused slots ----
        for (int h = tid; h < NHID; h += 192) {
            float v[SMAX];
            #pragma unroll
            for (int s = 0; s < SMAX; ++s) {
                const int q = c0 + s;
                v[s] = (q < mt) ? inputs[(size_t)sids[q] * NHID + h] : 0.0f;
            }
            float4* dst = (float4*)&xsT[h * SMAX];
            dst[0] = make_float4(v[0], v[1], v[2], v[3]);
            dst[1] = make_float4(v[4], v[5], v[6], v[7]);
        }
        __syncthreads();

        float4 acc[SMAX];
        #pragma unroll
        for (int s = 0; s < SMAX; ++s) acc[s] = make_float4(0, 0, 0, 0);

        // ---- W chunk pipeline: counted vmcnt, 4-8 loads always in flight ----
        #pragma unroll
        for (int c = 0; c < NCHUNK; ++c) {
            if (c < NCHUNK - 1) asm volatile("s_waitcnt vmcnt(4)" ::: "memory");
            else                asm volatile("s_waitcnt vmcnt(0)" ::: "memory");
            __builtin_amdgcn_sched_barrier(0);
            const float4* wf = (const float4*)((c & 1) ? wbase1 : wbase0);
            #pragma unroll
            for (int j = 0; j < 4; ++j) {
                const int r = hsel + 8 * j;              // row within chunk
                const float4 wv = wf[r * 8 + colg];      // f4 idx == lane: linear
                const float4 xa = xf[(c * CROWS + r) * 2];
                const float4 xb = xf[(c * CROWS + r) * 2 + 1];
                FMA4(acc[0], xa.x, wv); FMA4(acc[1], xa.y, wv);
                FMA4(acc[2], xa.z, wv); FMA4(acc[3], xa.w, wv);
                FMA4(acc[4], xb.x, wv); FMA4(acc[5], xb.y, wv);
                FMA4(acc[6], xb.z, wv); FMA4(acc[7], xb.w, wv);
            }
            if (c + 2 < NCHUNK) ISSUE(c + 2, (c & 1) ? wbase1 : wbase0);
        }

        // butterfly-reduce over hsel (masks 8,16,32): all lanes full sums
        #pragma unroll
        for (int s = 0; s < SMAX; ++s) {
            #pragma unroll
            for (int mm = 8; mm <= 32; mm <<= 1) {
                acc[s].x += __shfl_xor(acc[s].x, mm);
                acc[s].y += __shfl_xor(acc[s].y, mm);
                acc[s].z += __shfl_xor(acc[s].z, mm);
                acc[s].w += __shfl_xor(acc[s].w, mm);
            }
        }

        // per-sample softmax over 32 logits (8 colg lanes x 4 comps)
        #pragma unroll
        for (int s = 0; s < SMAX; ++s) {
            float4 a = acc[s];
            float mx = fmaxf(fmaxf(a.x, a.y), fmaxf(a.z, a.w));
            #pragma unroll
            for (int mm = 1; mm <= 4; mm <<= 1) mx = fmaxf(mx, __shfl_xor(mx, mm));
            float es = expf(a.x - mx) + expf(a.y - mx) + expf(a.z - mx) + expf(a.w - mx);
            #pragma unroll
            for (int mm = 1; mm <= 4; mm <<= 1) es += __shfl_xor(es, mm);

            const int step = (k == 2) ? (slab[c0 + s] & 31) : step01;
            const int e = step & 3;
            const float vv = (e == 0) ? a.x : (e == 1) ? a.y : (e == 2) ? a.z : a.w;
            const float sl = __shfl(vv, step >> 2);
            const float p = expf(sl - mx) / es;
            if (lane == 0) pk[k][s] = p;
        }
        __syncthreads();

        if (tid < SMAX && c0 + tid < mt)
            out[sids[c0 + tid]] = pk[0][tid] * pk[1][tid] * pk[2][tid];
    }
    #undef ISSUE
}

extern "C" void kernel_launch(void* const* d_in, const int* in_sizes, int n_in,
                              void* d_out, int out_size, void* d_ws, size_t ws_size,
                              hipStream_t stream)
{
    const float* inputs = (const float*)d_in[0];
    const int*   labels = (const int*)d_in[1];
    const float* W      = (const float*)d_in[2];
    float* out = (float*)d_out;

    hsm_bucket<<<dim3(NBUCK), dim3(192), 0, stream>>>(inputs, labels, W, out);
}